// Round 4
// baseline (228.639 us; speedup 1.0000x reference)
//
#include <hip/hip_runtime.h>
#include <stdint.h>

#define NPTS 8192
#define BATCH 4
#define CHUNK 512
#define GRID_CHAM (16 * 16 * 8)

typedef __attribute__((ext_vector_type(8))) short bf16x8;   // 8 bf16 = 4 VGPRs
typedef __attribute__((ext_vector_type(16))) float f32x16;  // 32x32 MFMA acc

__device__ __forceinline__ unsigned short f2bf(float x) {  // RNE fp32->bf16
  union { float f; unsigned u; } v; v.f = x;
  unsigned r = v.u + 0x7FFFu + ((v.u >> 16) & 1u);
  return (unsigned short)(r >> 16);
}
__device__ __forceinline__ float bf2f(unsigned short h) {
  union { float f; unsigned u; } v; v.u = ((unsigned)h) << 16;
  return v.f;
}

using as1_t = __attribute__((address_space(1))) const unsigned int;
using as3_t = __attribute__((address_space(3))) unsigned int;
__device__ __forceinline__ void lds_load16(const void* g, void* l) {
  __builtin_amdgcn_global_load_lds((as1_t*)g, (as3_t*)l, 16, 0, 0);
}

// Pack layout (fragment order): per 32-point tile T, 64 chunks of 16 B:
// chunk T*64 + h*32 + n holds K-slots [8h..8h+7] of point T*32+n.
// A-side (ref): k0-3=[-2x_h,-2x_h,-2x_l,-2x_l] k4-7=y k8-11=z k12-14=3-split(norm+pen) k15=0
// B-side (query): k0-3=[x_h,x_l,x_h,x_l] k4-7=y k8-11=z k12-14=[1,1,1] k15=0
// => D[ref m][query n] = (norm_r + pen) - 2 q.r   (query norm added in epilogue)
__device__ __forceinline__ void writeA(uint4* P, int T, int n,
                                       float x, float y, float z, float nn) {
  float ax = -2.f * x, ay = -2.f * y, az = -2.f * z;
  unsigned xh = f2bf(ax), xl = f2bf(ax - bf2f(xh));
  unsigned yh = f2bf(ay), yl = f2bf(ay - bf2f(yh));
  unsigned zh = f2bf(az), zl = f2bf(az - bf2f(zh));
  unsigned nh = f2bf(nn);
  float rem = nn - bf2f((unsigned short)nh);
  unsigned nm = f2bf(rem);
  unsigned nl = f2bf(rem - bf2f((unsigned short)nm));
  uint4 h0, h1;
  h0.x = xh | (xh << 16); h0.y = xl | (xl << 16);
  h0.z = yh | (yh << 16); h0.w = yl | (yl << 16);
  h1.x = zh | (zh << 16); h1.y = zl | (zl << 16);
  h1.z = nh | (nm << 16); h1.w = nl;
  P[T * 64 + n] = h0;
  P[T * 64 + 32 + n] = h1;
}
__device__ __forceinline__ void writeB(uint4* P, int T, int n,
                                       float x, float y, float z) {
  unsigned xh = f2bf(x), xl = f2bf(x - bf2f((unsigned short)xh));
  unsigned yh = f2bf(y), yl = f2bf(y - bf2f((unsigned short)yh));
  unsigned zh = f2bf(z), zl = f2bf(z - bf2f((unsigned short)zh));
  const unsigned ONE = 0x3F80u;
  unsigned ux = xh | (xl << 16), uy = yh | (yl << 16), uz = zh | (zl << 16);
  uint4 h0, h1;
  h0.x = ux; h0.y = ux; h0.z = uy; h0.w = uy;
  h1.x = uz; h1.y = uz; h1.z = ONE | (ONE << 16); h1.w = ONE;
  P[T * 64 + n] = h0;
  P[T * 64 + 32 + n] = h1;
}

__global__ __launch_bounds__(256) void prep_kernel(
    const float* __restrict__ pred, const float* __restrict__ target,
    const int* __restrict__ mask, const float* __restrict__ points,
    uint4* __restrict__ Apred, uint4* __restrict__ Aclean,
    uint4* __restrict__ Bclean, uint4* __restrict__ Bpred,
    float* __restrict__ qnClean, float* __restrict__ qnPred,
    float* __restrict__ min0, float* __restrict__ min1,
    float* __restrict__ l1part, unsigned int* __restrict__ counter) {
  int tid = threadIdx.x;
  int g = blockIdx.x * 256 + tid;  // 128 blocks x 256 = 32768 = BATCH*NPTS
  float px = pred[3 * g], py = pred[3 * g + 1], pz = pred[3 * g + 2];
  float tx = target[3 * g], ty = target[3 * g + 1], tz = target[3 * g + 2];
  float ox = points[3 * g], oy = points[3 * g + 1], oz = points[3 * g + 2];
  int m = mask[g];
  float cx = ox + tx, cy = oy + ty, cz = oz + tz;  // clean
  float qx = ox + px, qy = oy + py, qz = oz + pz;  // predicted denoised
  float cn = cx * cx + cy * cy + cz * cz;
  float qn = qx * qx + qy * qy + qz * qz;
  float pen = m ? 0.f : 1e9f;
  qnClean[g] = cn;
  qnPred[g] = qn;
  int T = g >> 5, n = g & 31;
  writeA(Apred, T, n, qx, qy, qz, qn + pen);   // dir0 refs = pred-denoised
  writeA(Aclean, T, n, cx, cy, cz, cn + pen);  // dir1 refs = clean
  writeB(Bclean, T, n, cx, cy, cz);            // dir0 queries = clean
  writeB(Bpred, T, n, qx, qy, qz);             // dir1 queries = pred-denoised
  min0[g] = 1e30f;
  min1[g] = 1e30f;
  if (g == 0) *counter = 0u;

  // per-block L1 partial (block spans a single b; final block sums l1part)
  float fm = (float)m;
  float l1c = fm * (fabsf(px - tx) + fabsf(py - ty) + fabsf(pz - tz)) * (1.f / 3.f);
  for (int off = 32; off; off >>= 1) l1c += __shfl_down(l1c, off);
  __shared__ float pl[4];
  if ((tid & 63) == 0) pl[tid >> 6] = l1c;
  __syncthreads();
  if (tid == 0) l1part[blockIdx.x] = pl[0] + pl[1] + pl[2] + pl[3];
}

__global__ __launch_bounds__(256, 4) void chamfer_kernel(
    const int* __restrict__ mask,
    const uint4* __restrict__ Apred, const uint4* __restrict__ Aclean,
    const uint4* __restrict__ Bclean, const uint4* __restrict__ Bpred,
    const float* __restrict__ qnClean, const float* __restrict__ qnPred,
    unsigned int* __restrict__ min0, unsigned int* __restrict__ min1,
    const float* __restrict__ l1part, unsigned int* __restrict__ counter,
    float* __restrict__ out) {
  __shared__ uint4 Asm[1024];  // 16 KB: 16 ref tiles
  __shared__ uint4 Bsm[1024];  // 16 KB: 16 query tiles
  int z = blockIdx.z, dir = z >> 2, b = z & 3;
  const uint4* __restrict__ Ag = dir ? Aclean : Apred;
  const uint4* __restrict__ Bg = dir ? Bpred : Bclean;
  const float* __restrict__ qn = dir ? qnPred : qnClean;
  unsigned int* __restrict__ outmin = dir ? min1 : min0;
  int jbase = blockIdx.x * CHUNK;  // refs
  int qbase = blockIdx.y * CHUNK;  // queries
  int tid = threadIdx.x;

  // stage: contiguous 16 KB regions, lane-consecutive 16 B chunks (wave-uniform
  // base + lane*16 -- matches global_load_lds semantics, conflict-free reads)
  const uint4* Agp = Ag + (size_t)(b * NPTS + jbase) * 2;
  const uint4* Bgp = Bg + (size_t)(b * NPTS + qbase) * 2;
#pragma unroll
  for (int it = 0; it < 4; it++) {
    lds_load16(Agp + it * 256 + tid, &Asm[it * 256 + tid]);
    lds_load16(Bgp + it * 256 + tid, &Bsm[it * 256 + tid]);
  }
  __syncthreads();  // drains vmcnt (global_load_lds) before LDS reads

  int lane = tid & 63, w = tid >> 6, n = lane & 31;
  const bf16x8* Al = (const bf16x8*)Asm;
  const bf16x8* Bl = (const bf16x8*)Bsm;
  bf16x8 bfr[4];
  float acc[4];
#pragma unroll
  for (int q = 0; q < 4; q++) {
    bfr[q] = Bl[(w * 4 + q) * 64 + lane];  // wave owns 4 query tiles (128 queries)
    acc[q] = 1e30f;
  }
  f32x16 zacc = {0.f, 0.f, 0.f, 0.f, 0.f, 0.f, 0.f, 0.f,
                 0.f, 0.f, 0.f, 0.f, 0.f, 0.f, 0.f, 0.f};

#pragma unroll 4
  for (int p = 0; p < 16; p++) {  // stream ref tiles
    bf16x8 af = Al[p * 64 + lane];
#pragma unroll
    for (int q = 0; q < 4; q++) {
      f32x16 d = __builtin_amdgcn_mfma_f32_32x32x16_bf16(af, bfr[q], zacc, 0, 0, 0);
      // 16 regs = 16 refs (rows) for this lane's query col -> 8 chained v_min3
      acc[q] = fminf(fminf(d[0], d[1]), acc[q]);
      acc[q] = fminf(fminf(d[2], d[3]), acc[q]);
      acc[q] = fminf(fminf(d[4], d[5]), acc[q]);
      acc[q] = fminf(fminf(d[6], d[7]), acc[q]);
      acc[q] = fminf(fminf(d[8], d[9]), acc[q]);
      acc[q] = fminf(fminf(d[10], d[11]), acc[q]);
      acc[q] = fminf(fminf(d[12], d[13]), acc[q]);
      acc[q] = fminf(fminf(d[14], d[15]), acc[q]);
    }
  }

  // epilogue: combine row-halves (lane>>5), add query norm, relu, atomicMin
#pragma unroll
  for (int q = 0; q < 4; q++) {
    float v = fminf(acc[q], __shfl_xor(acc[q], 32));
    int qi = qbase + (w * 4 + q) * 32 + n;
    if (lane < 32) {
      float val = fmaxf(v + qn[b * NPTS + qi], 0.f);
      atomicMin(&outmin[b * NPTS + qi], __float_as_uint(val));
    }
  }

  // ---- last-block fused final reduction (2 graph nodes total) ----
  __threadfence();
  __syncthreads();
  __shared__ int lastFlag;
  if (tid == 0) {
    unsigned int t = atomicAdd(counter, 1u);
    lastFlag = (t == GRID_CHAM - 1) ? 1 : 0;
  }
  __syncthreads();
  if (!lastFlag) return;
  __threadfence();

  __shared__ float r0[4], r1[4], r2[4];
  float cham = 0.f, msum = 0.f;  // meaningful on tid 0 only
  for (int bb = 0; bb < BATCH; bb++) {
    const int4* mk = (const int4*)(mask + bb * NPTS);
    const float4* m0 = (const float4*)((const float*)min0 + bb * NPTS);
    const float4* m1 = (const float4*)((const float*)min1 + bb * NPTS);
    float s0 = 0.f, s1 = 0.f, c = 0.f;
    for (int i = tid; i < NPTS / 4; i += 256) {
      int4 mm = mk[i];
      float4 a = m0[i];
      float4 e = m1[i];
      s0 += mm.x * a.x + mm.y * a.y + mm.z * a.z + mm.w * a.w;
      s1 += mm.x * e.x + mm.y * e.y + mm.z * e.z + mm.w * e.w;
      c += (float)(mm.x + mm.y + mm.z + mm.w);
    }
    for (int off = 32; off; off >>= 1) {
      s0 += __shfl_down(s0, off);
      s1 += __shfl_down(s1, off);
      c += __shfl_down(c, off);
    }
    if ((tid & 63) == 0) { r0[tid >> 6] = s0; r1[tid >> 6] = s1; r2[tid >> 6] = c; }
    __syncthreads();
    if (tid == 0) {
      float S0 = r0[0] + r0[1] + r0[2] + r0[3];
      float S1 = r1[0] + r1[1] + r1[2] + r1[3];
      float C = r2[0] + r2[1] + r2[2] + r2[3];
      cham += (S0 + S1) / fmaxf(C, 1.f);
      msum += C;
    }
    __syncthreads();
  }
  float l1s = (tid < 128) ? l1part[tid] : 0.f;
  for (int off = 32; off; off >>= 1) l1s += __shfl_down(l1s, off);
  if ((tid & 63) == 0) r0[tid >> 6] = l1s;
  __syncthreads();
  if (tid == 0) {
    l1s = r0[0] + r0[1] + r0[2] + r0[3];
    out[0] = 0.5f * (l1s / msum + cham * (1.f / BATCH));
  }
}

extern "C" void kernel_launch(void* const* d_in, const int* in_sizes, int n_in,
                              void* d_out, int out_size, void* d_ws, size_t ws_size,
                              hipStream_t stream) {
  const float* pred   = (const float*)d_in[0];
  const float* target = (const float*)d_in[1];
  const int*   mask   = (const int*)d_in[2];
  const float* points = (const float*)d_in[3];
  float* out = (float*)d_out;

  const int NP = BATCH * NPTS;  // 32768
  uint4* Apred  = (uint4*)d_ws;            // NP*2 chunks = 1 MB
  uint4* Aclean = Apred + NP * 2;
  uint4* Bclean = Aclean + NP * 2;
  uint4* Bpred  = Bclean + NP * 2;
  float* qnClean = (float*)(Bpred + NP * 2);
  float* qnPred  = qnClean + NP;
  float* min0    = qnPred + NP;
  float* min1    = min0 + NP;
  float* l1part  = min1 + NP;              // 128 floats
  unsigned int* counter = (unsigned int*)(l1part + 128);

  prep_kernel<<<NP / 256, 256, 0, stream>>>(
      pred, target, mask, points, Apred, Aclean, Bclean, Bpred,
      qnClean, qnPred, min0, min1, l1part, counter);

  dim3 grid(NPTS / CHUNK, NPTS / CHUNK, 2 * BATCH);  // (16,16,8) = 2048 blocks
  chamfer_kernel<<<grid, 256, 0, stream>>>(
      mask, Apred, Aclean, Bclean, Bpred, qnClean, qnPred,
      (unsigned int*)min0, (unsigned int*)min1, l1part, counter, out);
}

// Round 5
// 93.542 us; speedup vs baseline: 2.4442x; 2.4442x over previous
//
#include <hip/hip_runtime.h>
#include <stdint.h>

#define NPTS 8192
#define BATCH 4
#define CHUNK 512

typedef __attribute__((ext_vector_type(8))) short bf16x8;   // 8 bf16 = 4 VGPRs
typedef __attribute__((ext_vector_type(16))) float f32x16;  // 32x32 MFMA acc

struct Accum {
  float l1sum;
  float count[BATCH];
  float minsum[8];  // [dir*4+b]
  float pad[3];
};

__device__ __forceinline__ unsigned short f2bf(float x) {  // RNE fp32->bf16
  union { float f; unsigned u; } v; v.f = x;
  unsigned r = v.u + 0x7FFFu + ((v.u >> 16) & 1u);
  return (unsigned short)(r >> 16);
}
__device__ __forceinline__ float bf2f(unsigned short h) {
  union { float f; unsigned u; } v; v.u = ((unsigned)h) << 16;
  return v.f;
}

using as1_t = __attribute__((address_space(1))) const unsigned int;
using as3_t = __attribute__((address_space(3))) unsigned int;
__device__ __forceinline__ void lds_load16(const void* g, void* l) {
  __builtin_amdgcn_global_load_lds((as1_t*)g, (as3_t*)l, 16, 0, 0);
}

// Pack layout (fragment order): per 32-point tile T, 64 chunks of 16 B:
// chunk T*64 + h*32 + n = K-slots [8h..8h+7] of point T*32+n  (== chunk T*64+lane
// for MFMA lane = h*32+n, so frag load is lane-consecutive 16 B -> conflict-free).
// A (ref):   k0-3=[-2x_h,-2x_h,-2x_l,-2x_l] k4-7=y k8-11=z k12-14=3-split(norm+pen) k15=0
// B (query): k0-3=[x_h,x_l,x_h,x_l]         k4-7=y k8-11=z k12-14=[1,1,1]          k15=0
// => D[ref m][query n] = (norm_r + pen) - 2 q.r  (query norm added in epilogue;
// exact hi/lo bf16 product pairing, norm exact to ~4e-7)
__device__ __forceinline__ void writeA(uint4* P, int T, int n,
                                       float x, float y, float z, float nn) {
  float ax = -2.f * x, ay = -2.f * y, az = -2.f * z;
  unsigned xh = f2bf(ax), xl = f2bf(ax - bf2f(xh));
  unsigned yh = f2bf(ay), yl = f2bf(ay - bf2f(yh));
  unsigned zh = f2bf(az), zl = f2bf(az - bf2f(zh));
  unsigned nh = f2bf(nn);
  float rem = nn - bf2f((unsigned short)nh);
  unsigned nm = f2bf(rem);
  unsigned nl = f2bf(rem - bf2f((unsigned short)nm));
  uint4 h0, h1;
  h0.x = xh | (xh << 16); h0.y = xl | (xl << 16);
  h0.z = yh | (yh << 16); h0.w = yl | (yl << 16);
  h1.x = zh | (zh << 16); h1.y = zl | (zl << 16);
  h1.z = nh | (nm << 16); h1.w = nl;
  P[T * 64 + n] = h0;
  P[T * 64 + 32 + n] = h1;
}
__device__ __forceinline__ void writeB(uint4* P, int T, int n,
                                       float x, float y, float z) {
  unsigned xh = f2bf(x), xl = f2bf(x - bf2f((unsigned short)xh));
  unsigned yh = f2bf(y), yl = f2bf(y - bf2f((unsigned short)yh));
  unsigned zh = f2bf(z), zl = f2bf(z - bf2f((unsigned short)zh));
  const unsigned ONE = 0x3F80u;
  unsigned ux = xh | (xl << 16), uy = yh | (yl << 16), uz = zh | (zl << 16);
  uint4 h0, h1;
  h0.x = ux; h0.y = ux; h0.z = uy; h0.w = uy;
  h1.x = uz; h1.y = uz; h1.z = ONE | (ONE << 16); h1.w = ONE;
  P[T * 64 + n] = h0;
  P[T * 64 + 32 + n] = h1;
}

__global__ __launch_bounds__(256) void prep_kernel(
    const float* __restrict__ pred, const float* __restrict__ target,
    const int* __restrict__ mask, const float* __restrict__ points,
    uint4* __restrict__ Apred, uint4* __restrict__ Aclean,
    uint4* __restrict__ Bclean, uint4* __restrict__ Bpred,
    float* __restrict__ qnClean, float* __restrict__ qnPred,
    float* __restrict__ l1part, Accum* __restrict__ acc) {
  int tid = threadIdx.x;
  int g = blockIdx.x * 256 + tid;  // 128 blocks x 256 = BATCH*NPTS
  if (g < 16) ((float*)acc)[g] = 0.f;  // zero accumulators (read only by later nodes)
  float px = pred[3 * g], py = pred[3 * g + 1], pz = pred[3 * g + 2];
  float tx = target[3 * g], ty = target[3 * g + 1], tz = target[3 * g + 2];
  float ox = points[3 * g], oy = points[3 * g + 1], oz = points[3 * g + 2];
  int m = mask[g];
  float cx = ox + tx, cy = oy + ty, cz = oz + tz;  // clean
  float qx = ox + px, qy = oy + py, qz = oz + pz;  // predicted denoised
  float cn = cx * cx + cy * cy + cz * cz;
  float qn = qx * qx + qy * qy + qz * qz;
  float pen = m ? 0.f : 1e9f;
  qnClean[g] = cn;
  qnPred[g] = qn;
  int T = g >> 5, n = g & 31;
  writeA(Apred, T, n, qx, qy, qz, qn + pen);   // dir0 refs = pred-denoised
  writeA(Aclean, T, n, cx, cy, cz, cn + pen);  // dir1 refs = clean
  writeB(Bclean, T, n, cx, cy, cz);            // dir0 queries = clean
  writeB(Bpred, T, n, qx, qy, qz);             // dir1 queries = pred-denoised

  // per-block L1 partial (summed by final_kernel)
  float fm = (float)m;
  float l1c = fm * (fabsf(px - tx) + fabsf(py - ty) + fabsf(pz - tz)) * (1.f / 3.f);
  for (int off = 32; off; off >>= 1) l1c += __shfl_down(l1c, off);
  __shared__ float pl[4];
  if ((tid & 63) == 0) pl[tid >> 6] = l1c;
  __syncthreads();
  if (tid == 0) l1part[blockIdx.x] = pl[0] + pl[1] + pl[2] + pl[3];
}

// Block = (jchunk, qchunk, dir*4+b). Writes its 512 partial mins (qn added,
// relu'd -- both commute with min) to a PRIVATE slice of partial[]. No atomics,
// no fences: zero inter-block contention in the hot kernel.
__global__ __launch_bounds__(256) void chamfer_kernel(
    const uint4* __restrict__ Apred, const uint4* __restrict__ Aclean,
    const uint4* __restrict__ Bclean, const uint4* __restrict__ Bpred,
    const float* __restrict__ qnClean, const float* __restrict__ qnPred,
    float* __restrict__ partial) {
  __shared__ uint4 Asm[1024];  // 16 KB: 16 ref tiles
  int z = blockIdx.z, dir = z >> 2, b = z & 3;
  const uint4* __restrict__ Ag = dir ? Aclean : Apred;
  const uint4* __restrict__ Bg = dir ? Bpred : Bclean;
  const float* __restrict__ qn = dir ? qnPred : qnClean;
  int jx = blockIdx.x, jbase = jx * CHUNK;  // refs
  int qbase = blockIdx.y * CHUNK;           // queries
  int tid = threadIdx.x;

  // stage refs -> LDS (lane-consecutive 16 B chunks: global_load_lds-compatible)
  const uint4* Agp = Ag + (size_t)(b * NPTS + jbase) * 2;
#pragma unroll
  for (int it = 0; it < 4; it++) lds_load16(Agp + it * 256 + tid, &Asm[it * 256 + tid]);

  // query fragments straight from global (read once per wave; coalesced, L2-hot)
  int lane = tid & 63, w = tid >> 6, n = lane & 31;
  const bf16x8* Bb = (const bf16x8*)(Bg + (size_t)(b * NPTS + qbase) * 2);
  bf16x8 bfr[4];
  float acc[4];
#pragma unroll
  for (int q = 0; q < 4; q++) {
    bfr[q] = Bb[(w * 4 + q) * 64 + lane];  // wave owns 4 query tiles (128 queries)
    acc[q] = 1e30f;
  }
  __syncthreads();  // drains vmcnt: LDS staging + B loads both complete

  const bf16x8* Al = (const bf16x8*)Asm;
  f32x16 zacc = {0.f, 0.f, 0.f, 0.f, 0.f, 0.f, 0.f, 0.f,
                 0.f, 0.f, 0.f, 0.f, 0.f, 0.f, 0.f, 0.f};

#pragma unroll 4
  for (int p = 0; p < 16; p++) {  // stream ref tiles
    bf16x8 af = Al[p * 64 + lane];
#pragma unroll
    for (int q = 0; q < 4; q++) {
      f32x16 d = __builtin_amdgcn_mfma_f32_32x32x16_bf16(af, bfr[q], zacc, 0, 0, 0);
      // 16 regs = 16 refs (rows) for this lane's query col -> 8 chained v_min3
      acc[q] = fminf(fminf(d[0], d[1]), acc[q]);
      acc[q] = fminf(fminf(d[2], d[3]), acc[q]);
      acc[q] = fminf(fminf(d[4], d[5]), acc[q]);
      acc[q] = fminf(fminf(d[6], d[7]), acc[q]);
      acc[q] = fminf(fminf(d[8], d[9]), acc[q]);
      acc[q] = fminf(fminf(d[10], d[11]), acc[q]);
      acc[q] = fminf(fminf(d[12], d[13]), acc[q]);
      acc[q] = fminf(fminf(d[14], d[15]), acc[q]);
    }
  }

  // epilogue: combine row halves, add query norm, relu, plain coalesced store
  float* __restrict__ Pq = partial + ((size_t)(z * 16 + jx)) * NPTS + qbase;
#pragma unroll
  for (int q = 0; q < 4; q++) {
    float v = fminf(acc[q], __shfl_xor(acc[q], 32));
    int qi = (w * 4 + q) * 32 + n;
    if (lane < 32) Pq[qi] = fmaxf(v + qn[b * NPTS + qbase + qi], 0.f);
  }
}

// 64 blocks: 8 per (dir,b) slice. Min-fold 16 jchunk partials per query
// (coalesced stride-NPTS loads), mask, wave-reduce, one atomicAdd per block.
__global__ __launch_bounds__(256) void reduce_kernel(
    const int* __restrict__ mask, const float* __restrict__ partial,
    Accum* __restrict__ acc) {
  int slice = blockIdx.x >> 3, sub = blockIdx.x & 7;
  int dir = slice >> 2, bb = slice & 3;
  int t = threadIdx.x;
  const float* __restrict__ P = partial + (size_t)slice * 16 * NPTS + sub * 1024;
  float s = 0.f, c = 0.f;
  for (int i = t; i < 1024; i += 256) {
    float v = P[i];
#pragma unroll
    for (int jxx = 1; jxx < 16; jxx++) v = fminf(v, P[jxx * NPTS + i]);
    float m = (float)mask[bb * NPTS + sub * 1024 + i];
    s += m * v;
    c += m;
  }
  for (int off = 32; off; off >>= 1) {
    s += __shfl_down(s, off);
    c += __shfl_down(c, off);
  }
  __shared__ float rs[4], rc[4];
  int wave = t >> 6;
  if ((t & 63) == 0) { rs[wave] = s; rc[wave] = c; }
  __syncthreads();
  if (t == 0) {
    atomicAdd(&acc->minsum[slice], rs[0] + rs[1] + rs[2] + rs[3]);
    if (dir == 0) atomicAdd(&acc->count[bb], rc[0] + rc[1] + rc[2] + rc[3]);
  }
}

__global__ void final_kernel(const Accum* __restrict__ acc,
                             const float* __restrict__ l1part,
                             float* __restrict__ out) {
  int t = threadIdx.x;  // 128
  float l1 = l1part[t];
  for (int off = 32; off; off >>= 1) l1 += __shfl_down(l1, off);
  __shared__ float r[2];
  if ((t & 63) == 0) r[t >> 6] = l1;
  __syncthreads();
  if (t == 0) {
    float l1s = r[0] + r[1];
    float msum = 0.f, cham = 0.f;
#pragma unroll
    for (int b = 0; b < BATCH; b++) {
      msum += acc->count[b];
      cham += (acc->minsum[b] + acc->minsum[4 + b]) / fmaxf(acc->count[b], 1.f);
    }
    out[0] = 0.5f * (l1s / msum + cham * (1.f / BATCH));
  }
}

extern "C" void kernel_launch(void* const* d_in, const int* in_sizes, int n_in,
                              void* d_out, int out_size, void* d_ws, size_t ws_size,
                              hipStream_t stream) {
  const float* pred   = (const float*)d_in[0];
  const float* target = (const float*)d_in[1];
  const int*   mask   = (const int*)d_in[2];
  const float* points = (const float*)d_in[3];
  float* out = (float*)d_out;

  const int NP = BATCH * NPTS;  // 32768
  uint4* Apred  = (uint4*)d_ws;            // 1 MB each
  uint4* Aclean = Apred + NP * 2;
  uint4* Bclean = Aclean + NP * 2;
  uint4* Bpred  = Bclean + NP * 2;
  float* qnClean = (float*)(Bpred + NP * 2);   // 128 KB each
  float* qnPred  = qnClean + NP;
  float* partial = qnPred + NP;                // 8*16*NPTS floats = 4 MB
  float* l1part  = partial + 8 * 16 * NPTS;    // 128 floats
  Accum* acc     = (Accum*)(l1part + 128);

  prep_kernel<<<NP / 256, 256, 0, stream>>>(
      pred, target, mask, points, Apred, Aclean, Bclean, Bpred,
      qnClean, qnPred, l1part, acc);

  dim3 grid(NPTS / CHUNK, NPTS / CHUNK, 2 * BATCH);  // (16,16,8) = 2048 blocks
  chamfer_kernel<<<grid, 256, 0, stream>>>(
      Apred, Aclean, Bclean, Bpred, qnClean, qnPred, partial);

  reduce_kernel<<<64, 256, 0, stream>>>(mask, partial, acc);
  final_kernel<<<1, 128, 0, stream>>>(acc, l1part, out);
}